// Round 9
// baseline (191.127 us; speedup 1.0000x reference)
//
#include <hip/hip_runtime.h>

// SSIM, 64 slices of 512x512, 11x11 uniform window (separable box), zero pad.
// R11: deep pipeline via global_load_lds ring (no VGPR load destinations).
// Evidence: every round sits at 7-10 B/cyc/CU vmem — Little's law for
// drain-per-step (avg ~2KB outstanding/wave / ~900cyc latency). Fix = keep 16
// loads (2 full steps) in flight ALWAYS: loads go global->LDS (3-slot ring,
// 24KB/wave), compiler tracks no result => emits no waits; we own vmcnt via
// inline asm s_waitcnt vmcnt(N) + sched_barrier(0) (rule 18). LDS dest is
// linear, wave-uniform base + lane*16 (rule 21 satisfied, no swizzle).
// Fixes R10's ledger bug: o-row at slot s is valid only if s>=11 AND
// gs+s-11>=0 (slot 10 must subtract nothing).
// Single-wave blocks (no barriers), 2048 blocks, 6/CU (LDS-capped),
// XCD-clustered. DPP halo (R7), folded-K rational (R7), masked clamp loads (R9).
//
// vmcnt ledger (c=4 gload_lds, o=4; vmcnt retires in issue order):
//   prologue: issue c0,c1                         (8 outstanding)
//   warmup s=0..9: issue c(s+2); VW(8) -> c(s) landed; consumeW(s)
//   issue o10,o11                                 (16)
//   s=10: issue c12,o12 (24); VW(12) -> c10,c11,o10 landed; consumeS(10)
//   s=11..23: issue c,o(s+2) (+8); VW(16) -> c(s),o(s) landed; consumeS(s)
//   s=24: VW(8) -> c24,o24; s=25: VW(0) -> c25,o25.
// Ring safety: slot s (region s%3) consumed at step s; region rewritten by
// slot s+3, issued at step s+1 (after the consume, wave-sequential). c/o use
// disjoint offsets within a region.

constexpr int IMG   = 512;
constexpr int RB    = 16;                 // output rows per wave (band)
constexpr int BANDS = IMG / RB;           // 32
constexpr int NBLK  = 64 * BANDS;         // 2048 single-wave blocks
constexpr float K1 = 1.4641f;             // 0.01^2 * 121^2
constexpr float K2 = 13.1769f;            // 0.03^2 * 121^2

// DPP whole-wave shifts. wave_shr:1 -> lane i reads lane i-1 (lane 0 zero);
// wave_shl:1 -> lane i reads lane i+1 (lane 63 zero). Zero-fill == image pad.
__device__ __forceinline__ float shr1(float v) {
  return __int_as_float(__builtin_amdgcn_update_dpp(
      0, __float_as_int(v), 0x138, 0xF, 0xF, true));
}
__device__ __forceinline__ float shl1(float v) {
  return __int_as_float(__builtin_amdgcn_update_dpp(
      0, __float_as_int(v), 0x130, 0xF, 0xF, true));
}

// async global->LDS, 16B per lane; LDS write = uniform base + lane*16.
__device__ __forceinline__ void gl16(const float* g, float* l) {
  __builtin_amdgcn_global_load_lds(
      (const __attribute__((address_space(1))) void*)g,
      (__attribute__((address_space(3))) void*)l, 16, 0, 0);
}

// hand-counted wait; "memory" clobber + sched_barrier keep LDS reads below it.
#define VW(n) do {                                                             \
    asm volatile("s_waitcnt vmcnt(%0)" :: "n"(n) : "memory");                  \
    __builtin_amdgcn_sched_barrier(0);                                         \
  } while (0)

template <bool ATOMIC>
__global__ __launch_bounds__(64, 1) void ssim_main(const float* __restrict__ x,
                                                   const float* __restrict__ y,
                                                   float* __restrict__ out_ws) {
  // ring region (2048 floats): [cx 512][cy 512][ox 512][oy 512]; 3 regions.
  __shared__ float ring[3 * 2048];

  const int lane = threadIdx.x;            // single wave per block
  // XCD clustering: 8 slices per XCD; adjacent bands (10-row halo overlap)
  // are adjacent blocks -> same XCD -> halo re-reads L2-hot.
  const int bid  = blockIdx.x;
  const int xcd  = bid & 7;
  const int qq   = bid >> 3;               // 0..255
  const int z    = xcd * 8 + (qq >> 5);    // slice 0..63
  const int band = qq & 31;                // 0..31
  const int o0   = band * RB;
  const int gs   = o0 - 5;                 // first streamed input row

  const float* xs = x + (size_t)z * IMG * IMG;
  const float* ys = y + (size_t)z * IMG * IMG;
  const int l4 = lane * 4;                 // float offset for 16B load granule
  const int lw = lane * 8;                 // float offset of this lane's 8 cols

  float sX[8] = {}, sY[8] = {}, sXX[8] = {}, sYY[8] = {}, sXY[8] = {};
  float acc = 0.f;

  auto issue_c = [&](int slot) {
    const int gr  = gs + slot;
    const int grc = gr < 0 ? 0 : (gr > IMG - 1 ? IMG - 1 : gr);
    const int rb  = (slot % 3) * 2048;
    const float* gx = xs + grc * IMG + l4;
    const float* gy = ys + grc * IMG + l4;
    gl16(gx,       &ring[rb]);
    gl16(gx + 256, &ring[rb + 256]);
    gl16(gy,       &ring[rb + 512]);
    gl16(gy + 256, &ring[rb + 768]);
  };
  auto issue_o = [&](int slot) {
    const int gr  = gs + slot - 11;
    const int grc = gr < 0 ? 0 : (gr > IMG - 1 ? IMG - 1 : gr);
    const int rb  = (slot % 3) * 2048;
    const float* gx = xs + grc * IMG + l4;
    const float* gy = ys + grc * IMG + l4;
    gl16(gx,       &ring[rb + 1024]);
    gl16(gx + 256, &ring[rb + 1280]);
    gl16(gy,       &ring[rb + 1536]);
    gl16(gy + 256, &ring[rb + 1792]);
  };

  // Horizontal 11-tap window sums for one quantity (DPP halo).
  auto hwin = [&](const float (&S)[8], float (&B)[8]) {
    const float vm5  = shr1(S[3]);
    const float vm4  = shr1(S[4]);
    const float vm3  = shr1(S[5]);
    const float vm2  = shr1(S[6]);
    const float vm1  = shr1(S[7]);
    const float vp8  = shl1(S[0]);
    const float vp9  = shl1(S[1]);
    const float vp10 = shl1(S[2]);
    const float vp11 = shl1(S[3]);
    const float vp12 = shl1(S[4]);
    float s = (((vm5 + vm4) + (vm3 + vm2)) + ((vm1 + S[0]) + (S[1] + S[2]))) +
              ((S[3] + S[4]) + S[5]);
    B[0] = s;
    s += S[6]  - vm5;  B[1] = s;
    s += S[7]  - vm4;  B[2] = s;
    s += vp8   - vm3;  B[3] = s;
    s += vp9   - vm2;  B[4] = s;
    s += vp10  - vm1;  B[5] = s;
    s += vp11  - S[0]; B[6] = s;
    s += vp12  - S[1]; B[7] = s;
  };

  auto outp = [&]() {
    float bX[8], bY[8], bXX[8], bYY[8], bXY[8];
    hwin(sX, bX); hwin(sY, bY); hwin(sXX, bXX); hwin(sYY, bYY); hwin(sXY, bXY);
    // SSIM with 1/121 folded: (N1*N2)/(D1*D2), 121^4 cancels.
#pragma unroll
    for (int j = 0; j < 8; ++j) {
      const float bx  = bX[j];
      const float by  = bY[j];
      const float bxy = bx * by;
      const float sq  = fmaf(bx, bx, by * by);
      const float n1  = fmaf(2.f, bxy, K1);
      const float n2  = fmaf(242.f, bXY[j], fmaf(-2.f, bxy, K2));
      const float d1  = sq + K1;
      const float d2  = fmaf(121.f, bXX[j] + bYY[j], K2 - sq);
      acc += (n1 * n2) * __builtin_amdgcn_rcpf(d1 * d2);
    }
  };

  auto consumeW = [&](int slot) {
    const int rb = (slot % 3) * 2048;
    const float mc = ((unsigned)(gs + slot) < (unsigned)IMG) ? 1.f : 0.f;
    const float4 a = *(const float4*)&ring[rb + lw];
    const float4 b = *(const float4*)&ring[rb + lw + 4];
    const float4 c = *(const float4*)&ring[rb + 512 + lw];
    const float4 d = *(const float4*)&ring[rb + 512 + lw + 4];
    const float cx[8] = {a.x, a.y, a.z, a.w, b.x, b.y, b.z, b.w};
    const float cy[8] = {c.x, c.y, c.z, c.w, d.x, d.y, d.z, d.w};
#pragma unroll
    for (int j = 0; j < 8; ++j) {
      const float cxm = cx[j] * mc, cym = cy[j] * mc;
      sX[j] += cxm;
      sY[j] += cym;
      sXX[j] = fmaf(cx[j], cxm, sXX[j]);
      sYY[j] = fmaf(cy[j], cym, sYY[j]);
      sXY[j] = fmaf(cx[j], cym, sXY[j]);
    }
  };

  auto consumeS = [&](int slot) {
    const int rb = (slot % 3) * 2048;
    const float mc = ((unsigned)(gs + slot) < (unsigned)IMG) ? 1.f : 0.f;
    // o-row valid only if it was previously ADDED: s>=11 and row>=0 (R10 bugfix)
    const float mo = (slot >= 11 && (gs + slot - 11) >= 0) ? 1.f : 0.f;
    const float4 a = *(const float4*)&ring[rb + lw];
    const float4 b = *(const float4*)&ring[rb + lw + 4];
    const float4 c = *(const float4*)&ring[rb + 512 + lw];
    const float4 d = *(const float4*)&ring[rb + 512 + lw + 4];
    const float4 e = *(const float4*)&ring[rb + 1024 + lw];
    const float4 f = *(const float4*)&ring[rb + 1024 + lw + 4];
    const float4 g = *(const float4*)&ring[rb + 1536 + lw];
    const float4 h = *(const float4*)&ring[rb + 1536 + lw + 4];
    const float cx[8] = {a.x, a.y, a.z, a.w, b.x, b.y, b.z, b.w};
    const float cy[8] = {c.x, c.y, c.z, c.w, d.x, d.y, d.z, d.w};
    const float ox[8] = {e.x, e.y, e.z, e.w, f.x, f.y, f.z, f.w};
    const float oy[8] = {g.x, g.y, g.z, g.w, h.x, h.y, h.z, h.w};
#pragma unroll
    for (int j = 0; j < 8; ++j) {
      const float cxm = cx[j] * mc, cym = cy[j] * mc;
      const float oxm = ox[j] * mo, oym = oy[j] * mo;
      sX[j] += cxm - oxm;
      sY[j] += cym - oym;
      sXX[j] = fmaf(cx[j], cxm, fmaf(-ox[j], oxm, sXX[j]));
      sYY[j] = fmaf(cy[j], cym, fmaf(-oy[j], oym, sYY[j]));
      sXY[j] = fmaf(cx[j], cym, fmaf(-ox[j], oym, sXY[j]));
    }
    outp();
  };

  // ---- pipeline ----
  issue_c(0);
  issue_c(1);
#pragma unroll 1
  for (int s = 0; s < 10; ++s) {       // warmup: rows gs..gs+9
    issue_c(s + 2);
    VW(8);
    consumeW(s);
  }
  issue_o(10);
  issue_o(11);
  // s = 10 (first output row)
  issue_c(12);
  issue_o(12);
  VW(12);
  consumeS(10);
#pragma unroll 1
  for (int s = 11; s <= 23; ++s) {
    issue_c(s + 2);
    issue_o(s + 2);
    VW(16);
    consumeS(s);
  }
  VW(8);
  consumeS(24);
  VW(0);
  consumeS(25);

  // ---- reduction: single wave -> global ----
#pragma unroll
  for (int off = 32; off > 0; off >>= 1) acc += __shfl_down(acc, off, 64);
  if (lane == 0) {
    if (ATOMIC) {
      atomicAdd(out_ws, acc);
    } else {
      out_ws[bid] = acc;
    }
  }
}

__global__ void ssim_finalize(const float* __restrict__ partials, int n,
                              float* __restrict__ out) {
  __shared__ float wsum[4];
  float acc = 0.f;
  for (int i = threadIdx.x; i < n; i += 256) acc += partials[i];
#pragma unroll
  for (int off = 32; off > 0; off >>= 1) acc += __shfl_down(acc, off, 64);
  if ((threadIdx.x & 63) == 0) wsum[threadIdx.x >> 6] = acc;
  __syncthreads();
  if (threadIdx.x == 0) {
    const float t = wsum[0] + wsum[1] + wsum[2] + wsum[3];
    out[0] = 1.0f - t * (1.0f / (64.0f * 512.0f * 512.0f));
  }
}

__global__ void ssim_zero(float* p) {
  if (threadIdx.x == 0) p[0] = 0.f;
}

__global__ void ssim_finalize_atomic(const float* __restrict__ accp,
                                     float* __restrict__ out) {
  if (threadIdx.x == 0)
    out[0] = 1.0f - accp[0] * (1.0f / (64.0f * 512.0f * 512.0f));
}

extern "C" void kernel_launch(void* const* d_in, const int* in_sizes, int n_in,
                              void* d_out, int out_size, void* d_ws, size_t ws_size,
                              hipStream_t stream) {
  const float* x = (const float*)d_in[0];
  const float* y = (const float*)d_in[1];
  // d_in[2]: uniform 1/121 window, folded into K1/K2.
  float* out = (float*)d_out;

  dim3 grid(NBLK);      // 2048 single-wave blocks = 64 slices x 32 bands
  dim3 block(64);

  if (ws_size >= (size_t)NBLK * sizeof(float)) {
    float* partials = (float*)d_ws;
    ssim_main<false><<<grid, block, 0, stream>>>(x, y, partials);
    ssim_finalize<<<1, 256, 0, stream>>>(partials, NBLK, out);
  } else {
    float* accp = (float*)d_ws;
    ssim_zero<<<1, 64, 0, stream>>>(accp);
    ssim_main<true><<<grid, block, 0, stream>>>(x, y, accp);
    ssim_finalize_atomic<<<1, 64, 0, stream>>>(accp, out);
  }
}